// Round 1
// baseline (972.934 us; speedup 1.0000x reference)
//
#include <hip/hip_runtime.h>
#include <math.h>

// Problem constants
#define B_ 256
#define I_ 512
#define H_ 1024
#define M_ 128
#define A_ 2048
#define R_ 4
#define S_ 3
#define O_ 512
#define RS_ 512      // R*M
#define P_ 926       // R*(M+S+3) + 3*M+S+3
#define PW_OFF 536   // R*(M+S+3)

__device__ __forceinline__ float sigmoidf_(float x) { return 1.0f / (1.0f + expf(-x)); }
__device__ __forceinline__ float softplusf_(float x) {
    return (x > 20.0f) ? x : log1pf(expf(x));
}

// ---------------- block reductions (256 threads = 4 waves) ----------------
__device__ __forceinline__ float block_sum_(float v, float* red) {
    #pragma unroll
    for (int off = 32; off; off >>= 1) v += __shfl_down(v, off, 64);
    __syncthreads();                       // protect red reuse across calls
    if ((threadIdx.x & 63) == 0) red[threadIdx.x >> 6] = v;
    __syncthreads();
    return red[0] + red[1] + red[2] + red[3];
}
__device__ __forceinline__ float block_max_(float v, float* red) {
    #pragma unroll
    for (int off = 32; off; off >>= 1) v = fmaxf(v, __shfl_down(v, off, 64));
    __syncthreads();
    if ((threadIdx.x & 63) == 0) red[threadIdx.x >> 6] = v;
    __syncthreads();
    return fmaxf(fmaxf(red[0], red[1]), fmaxf(red[2], red[3]));
}

// ---------------- prep: xin = [x | read_vec_prev | h_prev]  (B,2048) -------
__global__ __launch_bounds__(256) void prep_kernel(
    const float* __restrict__ x, const float* __restrict__ rv,
    const float* __restrict__ hp, float* __restrict__ xin)
{
    int idx = blockIdx.x * 256 + threadIdx.x;   // B*2048
    int b = idx >> 11, j = idx & 2047;
    float v;
    if (j < 512)       v = x[b * 512 + j];
    else if (j < 1024) v = rv[b * 512 + (j - 512)];
    else               v = hp[b * 1024 + (j - 1024)];
    xin[idx] = v;
}

// ---------------- generic f32 GEMM: C = A@W (+bias) (+Cin) -----------------
// A: [M,K] row-major (lda), W: [K,N] row-major, C: [M,N]. M % 64 == 0, K % 16 == 0.
// NALIGN: N % 64 == 0 (no bounds checks, float4 W loads).
template<bool NALIGN>
__global__ __launch_bounds__(256) void gemm_f32_k(
    const float* __restrict__ A, int lda,
    const float* __restrict__ W,
    const float* __restrict__ bias,   // nullable
    const float* __restrict__ Cin,    // nullable
    float* __restrict__ C,
    int N, int K)
{
    __shared__ float As[16][64];
    __shared__ float Bs[16][64];
    int tid = threadIdx.x;
    int bm0 = blockIdx.y * 64, bn0 = blockIdx.x * 64;
    int tx = tid & 15, ty = tid >> 4;
    int arow = tid >> 2;          // 0..63
    int acol = (tid & 3) << 2;    // 0,4,8,12
    int wrow = tid >> 4;          // 0..15
    int wcol = (tid & 15) << 2;   // 0..60
    float acc[4][4] = {};

    for (int k0 = 0; k0 < K; k0 += 16) {
        float4 av = *(const float4*)(A + (size_t)(bm0 + arow) * lda + k0 + acol);
        As[acol + 0][arow] = av.x;
        As[acol + 1][arow] = av.y;
        As[acol + 2][arow] = av.z;
        As[acol + 3][arow] = av.w;
        const float* wp = W + (size_t)(k0 + wrow) * N + bn0 + wcol;
        if (NALIGN) {
            *(float4*)&Bs[wrow][wcol] = *(const float4*)wp;
        } else {
            int nc = bn0 + wcol;
            Bs[wrow][wcol + 0] = (nc + 0 < N) ? wp[0] : 0.0f;
            Bs[wrow][wcol + 1] = (nc + 1 < N) ? wp[1] : 0.0f;
            Bs[wrow][wcol + 2] = (nc + 2 < N) ? wp[2] : 0.0f;
            Bs[wrow][wcol + 3] = (nc + 3 < N) ? wp[3] : 0.0f;
        }
        __syncthreads();
        #pragma unroll
        for (int kk = 0; kk < 16; ++kk) {
            float a0 = As[kk][ty * 4 + 0], a1 = As[kk][ty * 4 + 1];
            float a2 = As[kk][ty * 4 + 2], a3 = As[kk][ty * 4 + 3];
            float b0 = Bs[kk][tx * 4 + 0], b1 = Bs[kk][tx * 4 + 1];
            float b2 = Bs[kk][tx * 4 + 2], b3 = Bs[kk][tx * 4 + 3];
            acc[0][0] += a0 * b0; acc[0][1] += a0 * b1; acc[0][2] += a0 * b2; acc[0][3] += a0 * b3;
            acc[1][0] += a1 * b0; acc[1][1] += a1 * b1; acc[1][2] += a1 * b2; acc[1][3] += a1 * b3;
            acc[2][0] += a2 * b0; acc[2][1] += a2 * b1; acc[2][2] += a2 * b2; acc[2][3] += a2 * b3;
            acc[3][0] += a3 * b0; acc[3][1] += a3 * b1; acc[3][2] += a3 * b2; acc[3][3] += a3 * b3;
        }
        __syncthreads();
    }
    #pragma unroll
    for (int i = 0; i < 4; ++i) {
        int r = bm0 + ty * 4 + i;
        #pragma unroll
        for (int j = 0; j < 4; ++j) {
            int col = bn0 + tx * 4 + j;
            if (NALIGN || col < N) {
                float v = acc[i][j];
                if (bias) v += bias[col];
                if (Cin)  v += Cin[(size_t)r * N + col];
                C[(size_t)r * N + col] = v;
            }
        }
    }
}

// ---------------- LSTM gates: h = sig(o)*tanh(sig(f)*c_prev + sig(i)*tanh(g))
__global__ __launch_bounds__(256) void gates_kernel(
    const float* __restrict__ z, const float* __restrict__ c_prev,
    float* __restrict__ h)
{
    int idx = blockIdx.x * 256 + threadIdx.x;   // B*H
    int b = idx >> 10, j = idx & 1023;
    const float* zb = z + (size_t)b * 4096;
    float zi = zb[j], zf = zb[1024 + j], zg = zb[2048 + j], zo = zb[3072 + j];
    float c = sigmoidf_(zf) * c_prev[idx] + sigmoidf_(zi) * tanhf(zg);
    h[idx] = sigmoidf_(zo) * tanhf(c);
}

// ---------------- pass 1: raw dots (5 heads) + column norms ----------------
// grid (A/256, B); thread owns one column a. Reads mem[b,:,a] once.
__global__ __launch_bounds__(256) void sim_kernel(
    const float* __restrict__ mem, const float* __restrict__ p,
    float* __restrict__ dots,   // [B,5,A]
    float* __restrict__ mn)     // [B,A]
{
    int b = blockIdx.y;
    int a = blockIdx.x * 256 + threadIdx.x;
    __shared__ float ks[5][M_];
    for (int idx = threadIdx.x; idx < 5 * M_; idx += 256) {
        int h = idx >> 7, m = idx & 127;
        ks[h][m] = p[(size_t)b * P_ + (h < 4 ? h * 134 + m : PW_OFF + m)];
    }
    __syncthreads();
    const float* mb = mem + (size_t)b * M_ * A_ + a;
    float d0 = 0, d1 = 0, d2 = 0, d3 = 0, d4 = 0, nn = 0;
    #pragma unroll 8
    for (int m = 0; m < M_; ++m) {
        float v = mb[(size_t)m * A_];
        d0 += v * ks[0][m]; d1 += v * ks[1][m]; d2 += v * ks[2][m];
        d3 += v * ks[3][m]; d4 += v * ks[4][m];
        nn += v * v;
    }
    size_t base = (size_t)b * 5 * A_ + a;
    dots[base + 0 * A_] = d0; dots[base + 1 * A_] = d1; dots[base + 2 * A_] = d2;
    dots[base + 3 * A_] = d3; dots[base + 4 * A_] = d4;
    mn[(size_t)b * A_ + a] = sqrtf(nn);
}

// ---------------- addressing: softmax -> gate -> shift -> sharpen ----------
// grid (5, B): head 0..3 = read heads, 4 = write head.
__global__ __launch_bounds__(256) void address_kernel(
    const float* __restrict__ p, const float* __restrict__ dots,
    const float* __restrict__ mn,
    const float* __restrict__ read_w_prev, const float* __restrict__ write_w_prev,
    float* __restrict__ w_read, float* __restrict__ w_write)
{
    int head = blockIdx.x;
    int b = blockIdx.y;
    int t = threadIdx.x;
    __shared__ float wg[A_];
    __shared__ float red[4];

    const float* pp = p + (size_t)b * P_ + (head < 4 ? head * 134 : PW_OFF);
    // scalar params (redundant per-thread, broadcast loads)
    float beta  = softplusf_(pp[128]);
    float g     = sigmoidf_(pp[129]);
    float gamma = 1.0f + softplusf_(pp[130]);
    float e0 = pp[131], e1 = pp[132], e2 = pp[133];
    float smax = fmaxf(e0, fmaxf(e1, e2));
    float x0 = expf(e0 - smax), x1 = expf(e1 - smax), x2 = expf(e2 - smax);
    float sden = x0 + x1 + x2;
    float s0 = x0 / sden, s1 = x1 / sden, s2 = x2 / sden;

    // ||k||
    float kacc = 0.0f;
    if (t < M_) { float kv = pp[t]; kacc = kv * kv; }
    float kn = sqrtf(block_sum_(kacc, red));

    const float* db = dots + ((size_t)b * 5 + head) * A_;
    const float* mb = mn + (size_t)b * A_;
    // logits
    float logit[8];
    float lmax = -1e30f;
    #pragma unroll
    for (int i = 0; i < 8; ++i) {
        int a = t + 256 * i;
        float sim = db[a] / (kn * mb[a] + 1e-8f);
        logit[i] = beta * sim;
        lmax = fmaxf(lmax, logit[i]);
    }
    lmax = block_max_(lmax, red);
    float ex[8]; float lsum = 0.0f;
    #pragma unroll
    for (int i = 0; i < 8; ++i) { ex[i] = expf(logit[i] - lmax); lsum += ex[i]; }
    lsum = block_sum_(lsum, red);
    float inv_lsum = 1.0f / lsum;

    const float* wprev = (head < 4) ? read_w_prev + ((size_t)b * 4 + head) * A_
                                    : write_w_prev + (size_t)b * A_;
    #pragma unroll
    for (int i = 0; i < 8; ++i) {
        int a = t + 256 * i;
        wg[a] = g * (ex[i] * inv_lsum) + (1.0f - g) * wprev[a];
    }
    __syncthreads();
    // circular shift (s over offsets -1,0,+1) then sharpen
    float wpow[8]; float psum = 0.0f;
    #pragma unroll
    for (int i = 0; i < 8; ++i) {
        int a = t + 256 * i;
        float ws = s0 * wg[(a + 1) & (A_ - 1)] + s1 * wg[a] + s2 * wg[(a + A_ - 1) & (A_ - 1)];
        float wp2 = powf(ws + 1e-12f, gamma);
        wpow[i] = wp2; psum += wp2;
    }
    psum = block_sum_(psum, red);
    float inv = 1.0f / (psum + 1e-8f);
    float* wout = (head < 4) ? w_read + ((size_t)b * 4 + head) * A_
                             : w_write + (size_t)b * A_;
    #pragma unroll
    for (int i = 0; i < 8; ++i) wout[t + 256 * i] = wpow[i] * inv;
}

// ---------------- pass 2: memory update + read vectors ---------------------
// grid (B*M): one block per (b,m) row of memory.
__global__ __launch_bounds__(256) void update_kernel(
    const float* __restrict__ mem, const float* __restrict__ p,
    const float* __restrict__ w_read, const float* __restrict__ w_write,
    float* __restrict__ mem_new,    // -> d_out + B*O
    float* __restrict__ read_vec)   // [B, R*M] (r-major)
{
    int bm = blockIdx.x;
    int b = bm >> 7, m = bm & 127;
    int t = threadIdx.x;
    const float* pw = p + (size_t)b * P_ + PW_OFF;
    float er = sigmoidf_(pw[134 + m]);
    float ad = pw[262 + m];
    const float* mrow = mem + ((size_t)b * M_ + m) * A_;
    const float* wwb  = w_write + (size_t)b * A_;
    const float* wr   = w_read + (size_t)b * 4 * A_;
    float* orow = mem_new + ((size_t)b * M_ + m) * A_;
    float s0 = 0, s1 = 0, s2 = 0, s3 = 0;
    #pragma unroll
    for (int i = 0; i < 8; ++i) {
        int a = t + 256 * i;
        float v = mrow[a];
        float ww = wwb[a];
        orow[a] = v * (1.0f - er * ww) + ad * ww;
        s0 += v * wr[a];
        s1 += v * wr[A_ + a];
        s2 += v * wr[2 * A_ + a];
        s3 += v * wr[3 * A_ + a];
    }
    __shared__ float red[4];
    s0 = block_sum_(s0, red);
    s1 = block_sum_(s1, red);
    s2 = block_sum_(s2, red);
    s3 = block_sum_(s3, red);
    if (t == 0) {
        float* rv = read_vec + (size_t)b * RS_ + m;
        rv[0 * M_] = s0; rv[1 * M_] = s1; rv[2 * M_] = s2; rv[3 * M_] = s3;
    }
}

extern "C" void kernel_launch(void* const* d_in, const int* in_sizes, int n_in,
                              void* d_out, int out_size, void* d_ws, size_t ws_size,
                              hipStream_t stream) {
    const float* x            = (const float*)d_in[0];
    const float* h_prev       = (const float*)d_in[1];
    const float* c_prev       = (const float*)d_in[2];
    const float* read_w_prev  = (const float*)d_in[3];
    const float* write_w_prev = (const float*)d_in[4];
    const float* memory_prev  = (const float*)d_in[5];
    const float* read_vec_prev= (const float*)d_in[6];
    const float* Wx           = (const float*)d_in[7];
    const float* Wh           = (const float*)d_in[8];
    const float* b_lstm       = (const float*)d_in[9];
    const float* Wo_h         = (const float*)d_in[10];
    const float* bo_h         = (const float*)d_in[11];
    const float* Wint         = (const float*)d_in[12];
    const float* b_int        = (const float*)d_in[13];
    const float* Wout         = (const float*)d_in[14];
    const float* b_out        = (const float*)d_in[15];
    float* out = (float*)d_out;                  // [B*O] ++ [B*M*A]
    float* mem_new_out = out + (size_t)B_ * O_;

    char* wsp = (char*)d_ws;
    float* xin      = (float*)wsp; wsp += (size_t)B_ * 2048 * 4;
    float* z        = (float*)wsp; wsp += (size_t)B_ * 4096 * 4;
    float* h        = (float*)wsp; wsp += (size_t)B_ * H_ * 4;
    float* p        = (float*)wsp; wsp += (size_t)B_ * P_ * 4;
    float* out_h    = (float*)wsp; wsp += (size_t)B_ * O_ * 4;
    float* dots     = (float*)wsp; wsp += (size_t)B_ * 5 * A_ * 4;
    float* mn       = (float*)wsp; wsp += (size_t)B_ * A_ * 4;
    float* w_read   = (float*)wsp; wsp += (size_t)B_ * R_ * A_ * 4;
    float* w_write  = (float*)wsp; wsp += (size_t)B_ * A_ * 4;
    float* read_vec = (float*)wsp; wsp += (size_t)B_ * RS_ * 4;

    // 1. xin = [x | read_vec_prev | h_prev]
    prep_kernel<<<dim3(B_ * 2048 / 256), dim3(256), 0, stream>>>(x, read_vec_prev, h_prev, xin);
    // 2. z = xin[:, :1024] @ Wx + b_lstm ; z += xin[:, 1024:] @ Wh
    gemm_f32_k<true><<<dim3(4096 / 64, B_ / 64), dim3(256), 0, stream>>>(
        xin, 2048, Wx, b_lstm, nullptr, z, 4096, 1024);
    gemm_f32_k<true><<<dim3(4096 / 64, B_ / 64), dim3(256), 0, stream>>>(
        xin + 1024, 2048, Wh, nullptr, z, z, 4096, 1024);
    // 3. gates -> h
    gates_kernel<<<dim3(B_ * H_ / 256), dim3(256), 0, stream>>>(z, c_prev, h);
    // 4. p = h @ Wint + b_int  (N=926, unaligned)
    gemm_f32_k<false><<<dim3((P_ + 63) / 64, B_ / 64), dim3(256), 0, stream>>>(
        h, H_, Wint, b_int, nullptr, p, P_, H_);
    // 5. out_h = h @ Wo_h + bo_h
    gemm_f32_k<true><<<dim3(O_ / 64, B_ / 64), dim3(256), 0, stream>>>(
        h, H_, Wo_h, bo_h, nullptr, out_h, O_, H_);
    // 6. dots + norms (one pass over memory)
    sim_kernel<<<dim3(A_ / 256, B_), dim3(256), 0, stream>>>(memory_prev, p, dots, mn);
    // 7. addressing for 4 read heads + 1 write head
    address_kernel<<<dim3(5, B_), dim3(256), 0, stream>>>(
        p, dots, mn, read_w_prev, write_w_prev, w_read, w_write);
    // 8. memory update + read vectors (second pass over memory)
    update_kernel<<<dim3(B_ * M_), dim3(256), 0, stream>>>(
        memory_prev, p, w_read, w_write, mem_new_out, read_vec);
    // 9. final_output = out_h + read_vec @ Wout + b_out
    gemm_f32_k<true><<<dim3(O_ / 64, B_ / 64), dim3(256), 0, stream>>>(
        read_vec, RS_, Wout, b_out, out_h, out, O_, RS_);
}

// Round 2
// 735.053 us; speedup vs baseline: 1.3236x; 1.3236x over previous
//
#include <hip/hip_runtime.h>
#include <math.h>

// Problem constants
#define B_ 256
#define I_ 512
#define H_ 1024
#define M_ 128
#define A_ 2048
#define R_ 4
#define S_ 3
#define O_ 512
#define RS_ 512      // R*M
#define P_ 926       // R*(M+S+3) + 3*M+S+3
#define PW_OFF 536   // R*(M+S+3)

typedef unsigned short ushort_t;
typedef __attribute__((ext_vector_type(8))) short bf16x8;
typedef __attribute__((ext_vector_type(4))) float f32x4;

__device__ __forceinline__ float sigmoidf_(float x) { return 1.0f / (1.0f + expf(-x)); }
__device__ __forceinline__ float softplusf_(float x) {
    return (x > 20.0f) ? x : log1pf(expf(x));
}
// f32 -> bf16 round-to-nearest-even
__device__ __forceinline__ ushort_t f2bf(float f) {
    unsigned int u = __float_as_uint(f);
    u = (u + 0x7FFFu + ((u >> 16) & 1u)) >> 16;
    return (ushort_t)u;
}

// ---------------- block reductions (256 threads = 4 waves) ----------------
__device__ __forceinline__ float block_sum_(float v, float* red) {
    #pragma unroll
    for (int off = 32; off; off >>= 1) v += __shfl_down(v, off, 64);
    __syncthreads();
    if ((threadIdx.x & 63) == 0) red[threadIdx.x >> 6] = v;
    __syncthreads();
    return red[0] + red[1] + red[2] + red[3];
}
__device__ __forceinline__ float block_max_(float v, float* red) {
    #pragma unroll
    for (int off = 32; off; off >>= 1) v = fmaxf(v, __shfl_down(v, off, 64));
    __syncthreads();
    if ((threadIdx.x & 63) == 0) red[threadIdx.x >> 6] = v;
    __syncthreads();
    return fmaxf(fmaxf(red[0], red[1]), fmaxf(red[2], red[3]));
}

// ---------------- prep: xin_bf = bf16([x | read_vec_prev | h_prev]) -------
__global__ __launch_bounds__(256) void prep_kernel(
    const float* __restrict__ x, const float* __restrict__ rv,
    const float* __restrict__ hp, ushort_t* __restrict__ xin)
{
    int idx = blockIdx.x * 256 + threadIdx.x;   // B*2048
    int b = idx >> 11, j = idx & 2047;
    float v;
    if (j < 512)       v = x[b * 512 + j];
    else if (j < 1024) v = rv[b * 512 + (j - 512)];
    else               v = hp[b * 1024 + (j - 1024)];
    xin[idx] = f2bf(v);
}

// ---------------- weight transpose+convert: W[K][N] f32 -> WT[N][ostride] bf16
// WT[n][koff + k] = W[k][n].  K % 32 == 0.
__global__ __launch_bounds__(256) void transpose_bf16_k(
    const float* __restrict__ W, ushort_t* __restrict__ WT,
    int K, int N, int ostride, int koff)
{
    __shared__ float tile[32][33];
    int k0 = blockIdx.y * 32, n0 = blockIdx.x * 32;
    int tx = threadIdx.x & 31, ty = threadIdx.x >> 5;  // ty 0..7
    #pragma unroll
    for (int i = 0; i < 4; ++i) {
        int k = ty + i * 8;
        int n = n0 + tx;
        float v = (n < N) ? W[(size_t)(k0 + k) * N + n] : 0.0f;
        tile[tx][k] = v;   // tile[n_local][k_local]
    }
    __syncthreads();
    #pragma unroll
    for (int i = 0; i < 4; ++i) {
        int nl = ty + i * 8;
        int n = n0 + nl;
        if (n < N) WT[(size_t)n * ostride + koff + k0 + tx] = f2bf(tile[nl][tx]);
    }
}

// ---------------- bf16 MFMA GEMM: C = A @ BT^T (+bias) (+Cin) --------------
// A: [M][lda] bf16 row-major; BT: [N][ldb] bf16 (= W^T, rows along K).
// C: [M][N] f32. M%64==0, K%32==0. NALIGN: N%64==0 (skip bounds checks).
// 64x64 tile, 4 waves each computing a 32x32 quadrant via 2x2 16x16x32 MFMAs.
template<bool NALIGN>
__global__ __launch_bounds__(256) void gemm_bf16_k(
    const ushort_t* __restrict__ A, int lda,
    const ushort_t* __restrict__ BT, int ldb,
    const float* __restrict__ bias,   // nullable
    const float* __restrict__ Cin,    // nullable
    float* __restrict__ C,
    int N, int K)
{
    __shared__ ushort_t As[64][40];   // pad 32->40 (80B rows: 2-way bank alias = free)
    __shared__ ushort_t Bs[64][40];
    int tid = threadIdx.x;
    int bm0 = blockIdx.y * 64, bn0 = blockIdx.x * 64;
    int srow = tid >> 2;              // staging: 64 rows x 4 threads x 8 elems
    int scol = (tid & 3) << 3;
    int wv = tid >> 6, l = tid & 63;
    int wm = (wv & 1) * 32, wn = (wv >> 1) * 32;
    int lane16 = l & 15, quad = l >> 4;

    f32x4 z4 = {0.0f, 0.0f, 0.0f, 0.0f};
    f32x4 acc00 = z4, acc01 = z4, acc10 = z4, acc11 = z4;

    const ushort_t* ap = A + (size_t)(bm0 + srow) * lda + scol;
    bool bvalid = NALIGN || (bn0 + srow) < N;
    const ushort_t* bp = BT + (size_t)(bn0 + srow) * ldb + scol;
    float4 fz = {0.0f, 0.0f, 0.0f, 0.0f};

    for (int k0 = 0; k0 < K; k0 += 32) {
        *(float4*)&As[srow][scol] = *(const float4*)(ap + k0);
        if (bvalid) *(float4*)&Bs[srow][scol] = *(const float4*)(bp + k0);
        else        *(float4*)&Bs[srow][scol] = fz;
        __syncthreads();
        bf16x8 a0 = *(const bf16x8*)&As[wm + lane16][quad * 8];
        bf16x8 a1 = *(const bf16x8*)&As[wm + 16 + lane16][quad * 8];
        bf16x8 b0 = *(const bf16x8*)&Bs[wn + lane16][quad * 8];
        bf16x8 b1 = *(const bf16x8*)&Bs[wn + 16 + lane16][quad * 8];
        acc00 = __builtin_amdgcn_mfma_f32_16x16x32_bf16(a0, b0, acc00, 0, 0, 0);
        acc01 = __builtin_amdgcn_mfma_f32_16x16x32_bf16(a0, b1, acc01, 0, 0, 0);
        acc10 = __builtin_amdgcn_mfma_f32_16x16x32_bf16(a1, b0, acc10, 0, 0, 0);
        acc11 = __builtin_amdgcn_mfma_f32_16x16x32_bf16(a1, b1, acc11, 0, 0, 0);
        __syncthreads();
    }

    // D layout: col = lane&15, row = quad*4 + reg
    #pragma unroll
    for (int gi = 0; gi < 2; ++gi) {
        #pragma unroll
        for (int gj = 0; gj < 2; ++gj) {
            const f32x4& acc = gi == 0 ? (gj == 0 ? acc00 : acc01)
                                       : (gj == 0 ? acc10 : acc11);
            int col = bn0 + wn + gj * 16 + lane16;
            if (NALIGN || col < N) {
                float badd = bias ? bias[col] : 0.0f;
                #pragma unroll
                for (int r2 = 0; r2 < 4; ++r2) {
                    int row = bm0 + wm + gi * 16 + quad * 4 + r2;
                    float v = acc[r2] + badd;
                    if (Cin) v += Cin[(size_t)row * N + col];
                    C[(size_t)row * N + col] = v;
                }
            }
        }
    }
}

// ---------------- LSTM gates: h = sig(o)*tanh(sig(f)*c_prev + sig(i)*tanh(g))
__global__ __launch_bounds__(256) void gates_kernel(
    const float* __restrict__ z, const float* __restrict__ c_prev,
    ushort_t* __restrict__ h)
{
    int idx = blockIdx.x * 256 + threadIdx.x;   // B*H
    int b = idx >> 10, j = idx & 1023;
    const float* zb = z + (size_t)b * 4096;
    float zi = zb[j], zf = zb[1024 + j], zg = zb[2048 + j], zo = zb[3072 + j];
    float c = sigmoidf_(zf) * c_prev[idx] + sigmoidf_(zi) * tanhf(zg);
    h[idx] = f2bf(sigmoidf_(zo) * tanhf(c));
}

// ---------------- pass 1: raw dots (5 heads) + column norms ----------------
__global__ __launch_bounds__(256) void sim_kernel(
    const float* __restrict__ mem, const float* __restrict__ p,
    float* __restrict__ dots,   // [B,5,A]
    float* __restrict__ mn)     // [B,A]
{
    int b = blockIdx.y;
    int a = blockIdx.x * 256 + threadIdx.x;
    __shared__ float ks[5][M_];
    for (int idx = threadIdx.x; idx < 5 * M_; idx += 256) {
        int h = idx >> 7, m = idx & 127;
        ks[h][m] = p[(size_t)b * P_ + (h < 4 ? h * 134 + m : PW_OFF + m)];
    }
    __syncthreads();
    const float* mb = mem + (size_t)b * M_ * A_ + a;
    float d0 = 0, d1 = 0, d2 = 0, d3 = 0, d4 = 0, nn = 0;
    #pragma unroll 8
    for (int m = 0; m < M_; ++m) {
        float v = mb[(size_t)m * A_];
        d0 += v * ks[0][m]; d1 += v * ks[1][m]; d2 += v * ks[2][m];
        d3 += v * ks[3][m]; d4 += v * ks[4][m];
        nn += v * v;
    }
    size_t base = (size_t)b * 5 * A_ + a;
    dots[base + 0 * A_] = d0; dots[base + 1 * A_] = d1; dots[base + 2 * A_] = d2;
    dots[base + 3 * A_] = d3; dots[base + 4 * A_] = d4;
    mn[(size_t)b * A_ + a] = sqrtf(nn);
}

// ---------------- addressing: softmax -> gate -> shift -> sharpen ----------
__global__ __launch_bounds__(256) void address_kernel(
    const float* __restrict__ p, const float* __restrict__ dots,
    const float* __restrict__ mn,
    const float* __restrict__ read_w_prev, const float* __restrict__ write_w_prev,
    float* __restrict__ w_read, float* __restrict__ w_write)
{
    int head = blockIdx.x;
    int b = blockIdx.y;
    int t = threadIdx.x;
    __shared__ float wg[A_];
    __shared__ float red[4];

    const float* pp = p + (size_t)b * P_ + (head < 4 ? head * 134 : PW_OFF);
    float beta  = softplusf_(pp[128]);
    float g     = sigmoidf_(pp[129]);
    float gamma = 1.0f + softplusf_(pp[130]);
    float e0 = pp[131], e1 = pp[132], e2 = pp[133];
    float smax = fmaxf(e0, fmaxf(e1, e2));
    float x0 = expf(e0 - smax), x1 = expf(e1 - smax), x2 = expf(e2 - smax);
    float sden = x0 + x1 + x2;
    float s0 = x0 / sden, s1 = x1 / sden, s2 = x2 / sden;

    float kacc = 0.0f;
    if (t < M_) { float kv = pp[t]; kacc = kv * kv; }
    float kn = sqrtf(block_sum_(kacc, red));

    const float* db = dots + ((size_t)b * 5 + head) * A_;
    const float* mb = mn + (size_t)b * A_;
    float logit[8];
    float lmax = -1e30f;
    #pragma unroll
    for (int i = 0; i < 8; ++i) {
        int a = t + 256 * i;
        float sim = db[a] / (kn * mb[a] + 1e-8f);
        logit[i] = beta * sim;
        lmax = fmaxf(lmax, logit[i]);
    }
    lmax = block_max_(lmax, red);
    float ex[8]; float lsum = 0.0f;
    #pragma unroll
    for (int i = 0; i < 8; ++i) { ex[i] = expf(logit[i] - lmax); lsum += ex[i]; }
    lsum = block_sum_(lsum, red);
    float inv_lsum = 1.0f / lsum;

    const float* wprev = (head < 4) ? read_w_prev + ((size_t)b * 4 + head) * A_
                                    : write_w_prev + (size_t)b * A_;
    #pragma unroll
    for (int i = 0; i < 8; ++i) {
        int a = t + 256 * i;
        wg[a] = g * (ex[i] * inv_lsum) + (1.0f - g) * wprev[a];
    }
    __syncthreads();
    float wpow[8]; float psum = 0.0f;
    #pragma unroll
    for (int i = 0; i < 8; ++i) {
        int a = t + 256 * i;
        float ws = s0 * wg[(a + 1) & (A_ - 1)] + s1 * wg[a] + s2 * wg[(a + A_ - 1) & (A_ - 1)];
        float wp2 = powf(ws + 1e-12f, gamma);
        wpow[i] = wp2; psum += wp2;
    }
    psum = block_sum_(psum, red);
    float inv = 1.0f / (psum + 1e-8f);
    float* wout = (head < 4) ? w_read + ((size_t)b * 4 + head) * A_
                             : w_write + (size_t)b * A_;
    #pragma unroll
    for (int i = 0; i < 8; ++i) wout[t + 256 * i] = wpow[i] * inv;
}

// ---------------- pass 2: memory update + read vectors ---------------------
// One block per (b,m). Each wave streams a 512-col quarter (update store) and
// keeps 4 register accumulators (one per read head); single __syncthreads.
__global__ __launch_bounds__(256) void update_kernel(
    const float* __restrict__ mem, const float* __restrict__ p,
    const float* __restrict__ w_read, const float* __restrict__ w_write,
    float* __restrict__ mem_new,      // -> d_out + B*O
    ushort_t* __restrict__ read_vec)  // [B, R*M] bf16
{
    int bm = blockIdx.x;
    int b = bm >> 7, m = bm & 127;
    int t = threadIdx.x;
    int wv = t >> 6, l = t & 63;
    const float* pw = p + (size_t)b * P_ + PW_OFF;
    float er = sigmoidf_(pw[134 + m]);
    float ad = pw[262 + m];
    const float* mrow = mem + ((size_t)b * M_ + m) * A_;
    const float* wwb  = w_write + (size_t)b * A_;
    const float* wr   = w_read + (size_t)b * 4 * A_;
    float* orow = mem_new + ((size_t)b * M_ + m) * A_;
    float s[4] = {0, 0, 0, 0};
    int abase = wv * 512 + l;
    #pragma unroll
    for (int i = 0; i < 8; ++i) {
        int a = abase + 64 * i;
        float v = mrow[a];
        float ww = wwb[a];
        orow[a] = v * (1.0f - er * ww) + ad * ww;
        s[0] += v * wr[a];
        s[1] += v * wr[A_ + a];
        s[2] += v * wr[2 * A_ + a];
        s[3] += v * wr[3 * A_ + a];
    }
    __shared__ float part[4][4];   // [wave][r]
    #pragma unroll
    for (int r = 0; r < 4; ++r) {
        float v = s[r];
        #pragma unroll
        for (int off = 32; off; off >>= 1) v += __shfl_down(v, off, 64);
        if (l == 0) part[wv][r] = v;
    }
    __syncthreads();
    if (t < 4) {
        float sum = part[0][t] + part[1][t] + part[2][t] + part[3][t];
        read_vec[(size_t)b * RS_ + t * M_ + m] = f2bf(sum);
    }
}

extern "C" void kernel_launch(void* const* d_in, const int* in_sizes, int n_in,
                              void* d_out, int out_size, void* d_ws, size_t ws_size,
                              hipStream_t stream) {
    const float* x            = (const float*)d_in[0];
    const float* h_prev       = (const float*)d_in[1];
    const float* c_prev       = (const float*)d_in[2];
    const float* read_w_prev  = (const float*)d_in[3];
    const float* write_w_prev = (const float*)d_in[4];
    const float* memory_prev  = (const float*)d_in[5];
    const float* read_vec_prev= (const float*)d_in[6];
    const float* Wx           = (const float*)d_in[7];
    const float* Wh           = (const float*)d_in[8];
    const float* b_lstm       = (const float*)d_in[9];
    const float* Wo_h         = (const float*)d_in[10];
    const float* bo_h         = (const float*)d_in[11];
    const float* Wint         = (const float*)d_in[12];
    const float* b_int        = (const float*)d_in[13];
    const float* Wout         = (const float*)d_in[14];
    const float* b_out        = (const float*)d_in[15];
    float* out = (float*)d_out;                  // [B*O] ++ [B*M*A]
    float* mem_new_out = out + (size_t)B_ * O_;

    char* wsp = (char*)d_ws;
    ushort_t* xin_bf = (ushort_t*)wsp; wsp += (size_t)B_ * 2048 * 2;
    float* z         = (float*)wsp;    wsp += (size_t)B_ * 4096 * 4;
    ushort_t* h_bf   = (ushort_t*)wsp; wsp += (size_t)B_ * H_ * 2;
    float* p         = (float*)wsp;    wsp += (size_t)B_ * P_ * 4;
    float* out_h     = (float*)wsp;    wsp += (size_t)B_ * O_ * 4;
    float* dots      = (float*)wsp;    wsp += (size_t)B_ * 5 * A_ * 4;
    float* mn        = (float*)wsp;    wsp += (size_t)B_ * A_ * 4;
    float* w_read    = (float*)wsp;    wsp += (size_t)B_ * R_ * A_ * 4;
    float* w_write   = (float*)wsp;    wsp += (size_t)B_ * A_ * 4;
    ushort_t* rv_bf  = (ushort_t*)wsp; wsp += (size_t)B_ * RS_ * 2;
    ushort_t* WxhT   = (ushort_t*)wsp; wsp += (size_t)4096 * 2048 * 2;
    ushort_t* WoT    = (ushort_t*)wsp; wsp += (size_t)512 * 1024 * 2;
    ushort_t* WintT  = (ushort_t*)wsp; wsp += (size_t)926 * 1024 * 2;
    ushort_t* WoutT  = (ushort_t*)wsp; wsp += (size_t)512 * 512 * 2;

    // Weight transposes (bf16): WT[n][k] = W[k][n]
    transpose_bf16_k<<<dim3(4096 / 32, 1024 / 32), 256, 0, stream>>>(Wx,   WxhT,  1024, 4096, 2048, 0);
    transpose_bf16_k<<<dim3(4096 / 32, 1024 / 32), 256, 0, stream>>>(Wh,   WxhT,  1024, 4096, 2048, 1024);
    transpose_bf16_k<<<dim3(512 / 32, 1024 / 32),  256, 0, stream>>>(Wo_h, WoT,   1024, 512,  1024, 0);
    transpose_bf16_k<<<dim3(29, 1024 / 32),        256, 0, stream>>>(Wint, WintT, 1024, 926,  1024, 0);
    transpose_bf16_k<<<dim3(512 / 32, 512 / 32),   256, 0, stream>>>(Wout, WoutT, 512,  512,  512,  0);

    // 1. xin_bf = bf16([x | read_vec_prev | h_prev])
    prep_kernel<<<dim3(B_ * 2048 / 256), 256, 0, stream>>>(x, read_vec_prev, h_prev, xin_bf);
    // 2. z = xin @ [Wx;Wh] + b_lstm   (single K=2048 bf16 MFMA GEMM)
    gemm_bf16_k<true><<<dim3(4096 / 64, B_ / 64), 256, 0, stream>>>(
        xin_bf, 2048, WxhT, 2048, b_lstm, nullptr, z, 4096, 2048);
    // 3. gates -> h (bf16)
    gates_kernel<<<dim3(B_ * H_ / 256), 256, 0, stream>>>(z, c_prev, h_bf);
    // 4. p = h @ Wint + b_int  (N=926)
    gemm_bf16_k<false><<<dim3(15, B_ / 64), 256, 0, stream>>>(
        h_bf, 1024, WintT, 1024, b_int, nullptr, p, P_, 1024);
    // 5. out_h = h @ Wo_h + bo_h
    gemm_bf16_k<true><<<dim3(O_ / 64, B_ / 64), 256, 0, stream>>>(
        h_bf, 1024, WoT, 1024, bo_h, nullptr, out_h, O_, 1024);
    // 6. dots + norms (one pass over memory)
    sim_kernel<<<dim3(A_ / 256, B_), 256, 0, stream>>>(memory_prev, p, dots, mn);
    // 7. addressing for 4 read heads + 1 write head
    address_kernel<<<dim3(5, B_), 256, 0, stream>>>(
        p, dots, mn, read_w_prev, write_w_prev, w_read, w_write);
    // 8. memory update + read vectors (second pass over memory)
    update_kernel<<<dim3(B_ * M_), 256, 0, stream>>>(
        memory_prev, p, w_read, w_write, mem_new_out, rv_bf);
    // 9. final_output = out_h + read_vec @ Wout + b_out
    gemm_bf16_k<true><<<dim3(O_ / 64, B_ / 64), 256, 0, stream>>>(
        rv_bf, 512, WoutT, 512, b_out, out_h, out, O_, 512);
}